// Round 10
// baseline (319.901 us; speedup 1.0000x reference)
//
#include <hip/hip_runtime.h>

#define D 128
typedef long long i64;
typedef unsigned short u16;
typedef unsigned int u32;
typedef __attribute__((ext_vector_type(8))) short bf16x8;
typedef __attribute__((ext_vector_type(4))) float f32x4;

#define RPB 512   // rows per bucket (dst >> 9)
#define CH 4096   // edges per chunk for hist/bin

__device__ inline float4 fma4(float a, float4 b, float4 c) {
  c.x = fmaf(a, b.x, c.x);
  c.y = fmaf(a, b.y, c.y);
  c.z = fmaf(a, b.z, c.z);
  c.w = fmaf(a, b.w, c.w);
  return c;
}

__device__ inline float4 bnrelu4(float4 v, float4 sc, float4 sh) {
  v.x = fmaxf(fmaf(v.x, sc.x, sh.x), 0.f);
  v.y = fmaxf(fmaf(v.y, sc.y, sh.y), 0.f);
  v.z = fmaxf(fmaf(v.z, sc.z, sh.z), 0.f);
  v.w = fmaxf(fmaf(v.w, sc.w, sh.w), 0.f);
  return v;
}

__device__ inline u16 f2bf(float f) {  // RNE f32->bf16
  union { float f; u32 u; } v; v.f = f;
  u32 r = (v.u + 0x7FFFu + ((v.u >> 16) & 1u)) >> 16;
  return (u16)r;
}

__device__ inline uint2 pk4(float4 v) {
  uint2 p;
  p.x = (u32)f2bf(v.x) | ((u32)f2bf(v.y) << 16);
  p.y = (u32)f2bf(v.z) | ((u32)f2bf(v.w) << 16);
  return p;
}

__device__ inline float4 unpk4(uint2 p) {
  float4 v;
  v.x = __uint_as_float(p.x << 16);
  v.y = __uint_as_float(p.x & 0xFFFF0000u);
  v.z = __uint_as_float(p.y << 16);
  v.w = __uint_as_float(p.y & 0xFFFF0000u);
  return v;
}

__device__ inline float4 ldbf4(const u16* __restrict__ feat, size_t row, int lane) {
  return unpk4(*(const uint2*)(feat + row * D + lane * 4));
}

// Detect int64-vs-int32 edge_index (odd u32 words all zero for int64 < 2^32).
__global__ void k_detect(const unsigned* __restrict__ w, int* __restrict__ flag) {
  __shared__ unsigned red[256];
  unsigned v = 0;
  for (int i = threadIdx.x; i < 2048; i += 256) v |= w[2 * i + 1];
  red[threadIdx.x] = v;
  __syncthreads();
  for (int s = 128; s > 0; s >>= 1) {
    if ((int)threadIdx.x < s) red[threadIdx.x] |= red[threadIdx.x + s];
    __syncthreads();
  }
  if (threadIdx.x == 0) *flag = (red[0] == 0u) ? 1 : 0;
}

// Pass A: per-chunk per-bucket histogram of dst. LDS atomics only.
__global__ __launch_bounds__(256) void k_hist(const int* __restrict__ ei32,
                                              const i64* __restrict__ ei64,
                                              const int* __restrict__ flag, int e,
                                              int nb, int* __restrict__ hist) {
  __shared__ int h[128];
  int c = blockIdx.x;
  int t = threadIdx.x;
  for (int i = t; i < nb; i += 256) h[i] = 0;
  __syncthreads();
  int is64 = *flag;
  long long base = (long long)c * CH;
  long long lim = base + CH < (long long)e ? base + CH : (long long)e;
  for (long long i = base + t; i < lim; i += 256) {
    int d = is64 ? (int)ei64[e + i] : ei32[e + i];
    atomicAdd(&h[d >> 9], 1);
  }
  __syncthreads();
  for (int i = t; i < nb; i += 256) hist[c * nb + i] = h[i];
}

// Pass B (1 block): chunkoff[c][b] = bucketbase[b] + prefix_c(hist[:,b]);
// bucketbase[0..nb] written out (bucketbase[nb] == e).
__global__ __launch_bounds__(128) void k_bscan(const int* __restrict__ hist,
                                               int nc, int nb,
                                               int* __restrict__ chunkoff,
                                               int* __restrict__ bucketbase) {
  __shared__ int tot[129];
  int b = threadIdx.x;
  if (b < nb) {
    int s = 0;
    for (int c = 0; c < nc; ++c) s += hist[c * nb + b];
    tot[b] = s;
  }
  __syncthreads();
  if (b == 0) {
    int run = 0;
    for (int i = 0; i < nb; ++i) { int v = tot[i]; tot[i] = run; run += v; }
    tot[nb] = run;
  }
  __syncthreads();
  if (b < nb) {
    int off = tot[b];
    for (int c = 0; c < nc; ++c) {
      chunkoff[c * nb + b] = off;
      off += hist[c * nb + b];
    }
  }
  if (b <= nb) bucketbase[b] = tot[b];
}

// Pass C: bin edges into bucket-grouped (dstlow<<16 | src) u32 pairs.
// Each block's run per bucket is a private contiguous span -> full-line writes.
__global__ __launch_bounds__(256) void k_bin(const int* __restrict__ ei32,
                                             const i64* __restrict__ ei64,
                                             const int* __restrict__ flag, int e,
                                             int nb, const int* __restrict__ chunkoff,
                                             u32* __restrict__ pairs) {
  __shared__ int cur[128];
  int c = blockIdx.x;
  int t = threadIdx.x;
  for (int i = t; i < nb; i += 256) cur[i] = chunkoff[c * nb + i];
  __syncthreads();
  int is64 = *flag;
  long long base = (long long)c * CH;
  long long lim = base + CH < (long long)e ? base + CH : (long long)e;
  for (long long i = base + t; i < lim; i += 256) {
    int s, d;
    if (is64) { s = (int)ei64[i]; d = (int)ei64[e + i]; }
    else      { s = ei32[i];      d = ei32[e + i]; }
    int slot = atomicAdd(&cur[d >> 9], 1);
    pairs[slot] = ((u32)(d & (RPB - 1)) << 16) | (u32)(u16)s;
  }
}

// Pass D: one block per bucket. LDS count (-> dis, rowptr ends) + LDS scan +
// LDS-cursor scatter of u16 src into this block's private csr span.
__global__ __launch_bounds__(512) void k_csr(const u32* __restrict__ pairs,
                                             const int* __restrict__ bucketbase,
                                             int n, int* __restrict__ rowptr,
                                             float* __restrict__ dis,
                                             u16* __restrict__ csr_src) {
  __shared__ int cnts[512];
  __shared__ int sbuf[512];
  __shared__ int cur[512];
  int b = blockIdx.x;
  int t = threadIdx.x;
  int base = bucketbase[b];
  int end = bucketbase[b + 1];
  cnts[t] = 0;
  __syncthreads();
  for (int i = base + t; i < end; i += 512)
    atomicAdd(&cnts[pairs[i] >> 16], 1);
  __syncthreads();
  int c0 = cnts[t];
  sbuf[t] = c0;
  __syncthreads();
  for (int off = 1; off < 512; off <<= 1) {
    int v = (t >= off) ? sbuf[t - off] : 0;
    __syncthreads();
    sbuf[t] += v;
    __syncthreads();
  }
  int incl = sbuf[t];
  int gr = b * RPB + t;
  if (gr < n) {
    rowptr[gr] = base + incl;           // row END (globally consistent)
    dis[gr] = rsqrtf((float)(c0 + 1));  // deg includes self-loop
  }
  cur[t] = incl - c0;                    // bucket-local exclusive start
  __syncthreads();
  for (int i = base + t; i < end; i += 512) {
    u32 p = pairs[i];
    int slot = atomicAdd(&cur[p >> 16], 1);
    csr_src[base + slot] = (u16)(p & 0xFFFFu);
  }
}

// Ybf[n x 128](bf16) = X @ W, MFMA bf16, f32 accum. X f32 (XBF=0) or bf16 (XBF=1).
// Block tile 128x128, 4 waves x 32 rows. BN: relu(x*scale+shift) fused on load.
#define GR 128
#define LDK 136  // padded bf16 leading dim: 272B rows, 16B-aligned, 2-way banks (free)
template <bool BN, bool XBF>
__global__ __launch_bounds__(256) void k_gemm(const float* __restrict__ Xf,
                                              const u16* __restrict__ Xb,
                                              const float* __restrict__ W,
                                              u16* __restrict__ Ybf, int n,
                                              const float* __restrict__ scale,
                                              const float* __restrict__ shift) {
  __shared__ u16 Xl[GR * LDK];   // ~34 KB
  __shared__ u16 Wt[128 * LDK];  // ~34 KB
  int t = threadIdx.x;
  int row0 = blockIdx.x * GR;
  {  // stage Wt transposed (bf16)
    int kk = t >> 5;
    int c4 = (t & 31) << 2;
    for (int k = kk; k < 128; k += 8) {
      float4 w = *(const float4*)&W[k * D + c4];
      Wt[(c4 + 0) * LDK + k] = f2bf(w.x);
      Wt[(c4 + 1) * LDK + k] = f2bf(w.y);
      Wt[(c4 + 2) * LDK + k] = f2bf(w.z);
      Wt[(c4 + 3) * LDK + k] = f2bf(w.w);
    }
  }
  {  // stage Xl (bf16), optional BN+relu
    int r = t >> 5;
    int c4 = (t & 31) << 2;
    float4 sc, sh;
    if (BN) { sc = ((const float4*)scale)[t & 31]; sh = ((const float4*)shift)[t & 31]; }
    for (int rr = r; rr < GR; rr += 8) {
      int gr = row0 + rr;
      uint2 pk = {0u, 0u};
      if (gr < n) {
        if (XBF) {
          pk = *(const uint2*)&Xb[(size_t)gr * D + c4];
          if (BN) pk = pk4(bnrelu4(unpk4(pk), sc, sh));
        } else {
          float4 v = *(const float4*)&Xf[(size_t)gr * D + c4];
          if (BN) v = bnrelu4(v, sc, sh);
          pk = pk4(v);
        }
      }
      *(uint2*)&Xl[rr * LDK + c4] = pk;
    }
  }
  __syncthreads();
  int wv = t >> 6;
  int l = t & 63;
  int lg = l >> 4;
  int li = l & 15;
  int wr = wv * 32;
  f32x4 acc[2][8];
#pragma unroll
  for (int m = 0; m < 2; ++m)
#pragma unroll
    for (int nf = 0; nf < 8; ++nf)
      acc[m][nf] = (f32x4){0.f, 0.f, 0.f, 0.f};
#pragma unroll
  for (int ks = 0; ks < 4; ++ks) {
    int k0 = ks * 32 + lg * 8;
    bf16x8 a0 = *(const bf16x8*)&Xl[(wr + li) * LDK + k0];
    bf16x8 a1 = *(const bf16x8*)&Xl[(wr + 16 + li) * LDK + k0];
#pragma unroll
    for (int nf = 0; nf < 8; ++nf) {
      bf16x8 b = *(const bf16x8*)&Wt[(nf * 16 + li) * LDK + k0];
      acc[0][nf] = __builtin_amdgcn_mfma_f32_16x16x32_bf16(a0, b, acc[0][nf], 0, 0, 0);
      acc[1][nf] = __builtin_amdgcn_mfma_f32_16x16x32_bf16(a1, b, acc[1][nf], 0, 0, 0);
    }
  }
#pragma unroll
  for (int m = 0; m < 2; ++m) {
#pragma unroll
    for (int r = 0; r < 4; ++r) {
      int grow = row0 + wr + 16 * m + lg * 4 + r;
      if (grow < n) {
        u16* orow = Ybf + (size_t)grow * D;
#pragma unroll
        for (int nf = 0; nf < 8; ++nf)
          orow[nf * 16 + li] = f2bf(acc[m][nf][r]);
      }
    }
  }
}

// Pull-gather, one 32-lane group per dst row, grid-stride over rows.
// L2=false (layer1): out bf16 h1pre; accumulate BN col-stats -> block partials.
// L2=true  (layer2): skip = relu(BN(h1bf)) added; out f32 (final).
template <bool L2>
__global__ __launch_bounds__(256) void k_gather(const u16* __restrict__ feat,
                                                const u16* __restrict__ h1bf,
                                                const float* __restrict__ bias,
                                                const float* __restrict__ dis,
                                                const int* __restrict__ rowptr,
                                                const u16* __restrict__ csr_src,
                                                float* __restrict__ outf,
                                                u16* __restrict__ outb, int n,
                                                const float* __restrict__ scale,
                                                const float* __restrict__ shift,
                                                float* __restrict__ partial) {
  __shared__ float s_l[8][128];
  __shared__ float q_l[8][128];
  int t = threadIdx.x;
  int lane = t & 31;
  int g = t >> 5;
  int ngroups = gridDim.x * 8;
  float4 s4 = {0.f, 0.f, 0.f, 0.f};
  float4 q4 = {0.f, 0.f, 0.f, 0.f};
  float4 bv = ((const float4*)bias)[lane];
  float4 sc, sh;
  if (L2) { sc = ((const float4*)scale)[lane]; sh = ((const float4*)shift)[lane]; }
  for (int r = blockIdx.x * 8 + g; r < n; r += ngroups) {
    int start = (r == 0) ? 0 : rowptr[r - 1];
    int end = rowptr[r];
    float dr = dis[r];
    float4 acc = bv;
    float4 sv = ldbf4(feat, (size_t)r, lane);
    acc = fma4(dr * dr, sv, acc);
    if (L2) {
      float4 h = bnrelu4(ldbf4(h1bf, (size_t)r, lane), sc, sh);
      acc.x += h.x; acc.y += h.y; acc.z += h.z; acc.w += h.w;
    }
    float4 acc1 = {0.f, 0.f, 0.f, 0.f};
    int j = start;
    for (; j + 4 <= end; j += 4) {
      int s0 = csr_src[j];
      int s1 = csr_src[j + 1];
      int s2 = csr_src[j + 2];
      int s3 = csr_src[j + 3];
      float w0 = dis[s0] * dr;
      float w1 = dis[s1] * dr;
      float w2 = dis[s2] * dr;
      float w3 = dis[s3] * dr;
      float4 v0 = ldbf4(feat, (size_t)s0, lane);
      float4 v1 = ldbf4(feat, (size_t)s1, lane);
      float4 v2 = ldbf4(feat, (size_t)s2, lane);
      float4 v3 = ldbf4(feat, (size_t)s3, lane);
      acc = fma4(w0, v0, acc);
      acc1 = fma4(w1, v1, acc1);
      acc = fma4(w2, v2, acc);
      acc1 = fma4(w3, v3, acc1);
    }
    for (; j < end; ++j) {
      int s0 = csr_src[j];
      float w0 = dis[s0] * dr;
      acc = fma4(w0, ldbf4(feat, (size_t)s0, lane), acc);
    }
    acc.x += acc1.x; acc.y += acc1.y; acc.z += acc1.z; acc.w += acc1.w;
    if (L2) {
      ((float4*)(outf + (size_t)r * D))[lane] = acc;
    } else {
      *(uint2*)(outb + (size_t)r * D + lane * 4) = pk4(acc);
      s4.x += acc.x; s4.y += acc.y; s4.z += acc.z; s4.w += acc.w;
      q4.x = fmaf(acc.x, acc.x, q4.x);
      q4.y = fmaf(acc.y, acc.y, q4.y);
      q4.z = fmaf(acc.z, acc.z, q4.z);
      q4.w = fmaf(acc.w, acc.w, q4.w);
    }
  }
  if (!L2) {
    *(float4*)&s_l[g][lane * 4] = s4;
    *(float4*)&q_l[g][lane * 4] = q4;
    __syncthreads();
    float v = 0.f;
    if (t < 128) {
#pragma unroll
      for (int gg = 0; gg < 8; ++gg) v += s_l[gg][t];
    } else {
#pragma unroll
      for (int gg = 0; gg < 8; ++gg) v += q_l[gg][t - 128];
    }
    partial[blockIdx.x * 256 + t] = v;  // [0..127]=colsum, [128..255]=colsumsq
  }
}

// Fold block partials -> mu/var -> scale/shift. One block per column.
__global__ __launch_bounds__(256) void k_bnreduce(const float* __restrict__ partial,
                                                  int nbp,
                                                  const float* __restrict__ gamma,
                                                  const float* __restrict__ beta,
                                                  float* __restrict__ scale,
                                                  float* __restrict__ shift, int n) {
  __shared__ float rs[256], rq[256];
  int c = blockIdx.x;
  int t = threadIdx.x;
  float s = 0.f, q = 0.f;
  for (int b = t; b < nbp; b += 256) {
    s += partial[b * 256 + c];
    q += partial[b * 256 + 128 + c];
  }
  rs[t] = s; rq[t] = q;
  __syncthreads();
  for (int st = 128; st > 0; st >>= 1) {
    if (t < st) { rs[t] += rs[t + st]; rq[t] += rq[t + st]; }
    __syncthreads();
  }
  if (t == 0) {
    float inv_n = 1.0f / (float)n;
    float mu = rs[0] * inv_n;
    float var = rq[0] * inv_n - mu * mu;
    float sc = gamma[c] * rsqrtf(var + 1e-5f);
    scale[c] = sc;
    shift[c] = beta[c] - mu * sc;
  }
}

extern "C" void kernel_launch(void* const* d_in, const int* in_sizes, int n_in,
                              void* d_out, int out_size, void* d_ws, size_t ws_size,
                              hipStream_t stream) {
  const float* x     = (const float*)d_in[0];
  const int*   ei32  = (const int*)d_in[1];
  const i64*   ei64  = (const i64*)d_in[1];
  const float* W1    = (const float*)d_in[2];
  const float* b1    = (const float*)d_in[3];
  const float* W2    = (const float*)d_in[4];
  const float* b2    = (const float*)d_in[5];
  const float* gamma = (const float*)d_in[6];
  const float* beta  = (const float*)d_in[7];
  float* out = (float*)d_out;

  const int n = in_sizes[0] / D;  // 50000
  const int e = in_sizes[1] / 2;  // 800000
  const int GB1 = 1024;           // persistent gather1 blocks (stats partials)
  const int NB = (n + RPB - 1) / RPB;  // buckets (98)
  const int NC = (e + CH - 1) / CH;    // chunks (196)

  // Workspace layout (~30 MB)
  size_t npad = ((size_t)n + 255) & ~255ULL;
  size_t epad = ((size_t)e + 255) & ~255ULL;
  char* p = (char*)d_ws;
  float* dis      = (float*)p; p += npad * 4;
  int*   rowptr   = (int*)p;   p += npad * 4;
  u16*   csr16    = (u16*)p;   p += epad * 2;
  u32*   pairs    = (u32*)p;   p += epad * 4;
  int*   hist     = (int*)p;   p += (size_t)NC * NB * 4;
  int*   chunkoff = (int*)p;   p += (size_t)NC * NB * 4;
  int*   bucketbase = (int*)p; p += ((size_t)NB + 1 + 63) / 64 * 64 * 4;
  u16*   hwbf     = (u16*)p;   p += (size_t)n * D * 2;  // gemm out (hw1, then hw2)
  u16*   h1bf     = (u16*)p;   p += (size_t)n * D * 2;  // h1pre (bf16)
  float* partial  = (float*)p; p += (size_t)GB1 * 256 * 4;
  float* scale    = (float*)p; p += D * 4;
  float* shift    = (float*)p; p += D * 4;
  int*   flag     = (int*)p;   p += 256 * 4;

  int gb = (n + 7) / 8;          // gather2: 8 rows per 256-thread block
  int mb = (n + GR - 1) / GR;    // gemm: 128 rows per block

  // CSR build: atomic-free bucket sort (LDS-local randomness only)
  k_detect<<<1, 256, 0, stream>>>((const unsigned*)d_in[1], flag);
  k_hist<<<NC, 256, 0, stream>>>(ei32, ei64, flag, e, NB, hist);
  k_bscan<<<1, 128, 0, stream>>>(hist, NC, NB, chunkoff, bucketbase);
  k_bin<<<NC, 256, 0, stream>>>(ei32, ei64, flag, e, NB, chunkoff, pairs);
  k_csr<<<NB, 512, 0, stream>>>(pairs, bucketbase, n, rowptr, dis, csr16);

  // layer 1: conv (MFMA) -> gather (+fused BN stats) -> scale/shift
  k_gemm<false, false><<<mb, 256, 0, stream>>>(x, nullptr, W1, hwbf, n, nullptr, nullptr);
  k_gather<false><<<GB1, 256, 0, stream>>>(hwbf, nullptr, b1, dis, rowptr, csr16,
                                           nullptr, h1bf, n, nullptr, nullptr, partial);
  k_bnreduce<<<D, 256, 0, stream>>>(partial, GB1, gamma, beta, scale, shift, n);

  // layer 2: conv (BN+relu fused, bf16 in) + gather with fused BN'd skip
  k_gemm<true, true><<<mb, 256, 0, stream>>>(nullptr, h1bf, W2, hwbf, n, scale, shift);
  k_gather<true><<<gb, 256, 0, stream>>>(hwbf, h1bf, b2, dis, rowptr, csr16,
                                         out, nullptr, n, scale, shift, nullptr);
}

// Round 11
// 263.277 us; speedup vs baseline: 1.2151x; 1.2151x over previous
//
#include <hip/hip_runtime.h>

#define D 128
typedef long long i64;
typedef unsigned short u16;
typedef unsigned int u32;
typedef __attribute__((ext_vector_type(8))) short bf16x8;
typedef __attribute__((ext_vector_type(4))) float f32x4;

#define RPB 512    // rows per bucket (dst >> 9)
#define CH 4096    // edges per chunk for hist/bin
#define MAXHB 19712  // max NC*NB ints LDS-resident in k_bscan (~77 KB)

__device__ inline float4 fma4(float a, float4 b, float4 c) {
  c.x = fmaf(a, b.x, c.x);
  c.y = fmaf(a, b.y, c.y);
  c.z = fmaf(a, b.z, c.z);
  c.w = fmaf(a, b.w, c.w);
  return c;
}

__device__ inline float4 bnrelu4(float4 v, float4 sc, float4 sh) {
  v.x = fmaxf(fmaf(v.x, sc.x, sh.x), 0.f);
  v.y = fmaxf(fmaf(v.y, sc.y, sh.y), 0.f);
  v.z = fmaxf(fmaf(v.z, sc.z, sh.z), 0.f);
  v.w = fmaxf(fmaf(v.w, sc.w, sh.w), 0.f);
  return v;
}

__device__ inline u16 f2bf(float f) {  // RNE f32->bf16
  union { float f; u32 u; } v; v.f = f;
  u32 r = (v.u + 0x7FFFu + ((v.u >> 16) & 1u)) >> 16;
  return (u16)r;
}

__device__ inline uint2 pk4(float4 v) {
  uint2 p;
  p.x = (u32)f2bf(v.x) | ((u32)f2bf(v.y) << 16);
  p.y = (u32)f2bf(v.z) | ((u32)f2bf(v.w) << 16);
  return p;
}

__device__ inline float4 unpk4(uint2 p) {
  float4 v;
  v.x = __uint_as_float(p.x << 16);
  v.y = __uint_as_float(p.x & 0xFFFF0000u);
  v.z = __uint_as_float(p.y << 16);
  v.w = __uint_as_float(p.y & 0xFFFF0000u);
  return v;
}

__device__ inline float4 ldbf4(const u16* __restrict__ feat, size_t row, int lane) {
  return unpk4(*(const uint2*)(feat + row * D + lane * 4));
}

// Detect int64-vs-int32 edge_index (odd u32 words all zero for int64 < 2^32).
__global__ void k_detect(const unsigned* __restrict__ w, int* __restrict__ flag) {
  __shared__ unsigned red[256];
  unsigned v = 0;
  for (int i = threadIdx.x; i < 2048; i += 256) v |= w[2 * i + 1];
  red[threadIdx.x] = v;
  __syncthreads();
  for (int s = 128; s > 0; s >>= 1) {
    if ((int)threadIdx.x < s) red[threadIdx.x] |= red[threadIdx.x + s];
    __syncthreads();
  }
  if (threadIdx.x == 0) *flag = (red[0] == 0u) ? 1 : 0;
}

// Pass A: per-chunk per-bucket histogram of dst. LDS atomics only.
__global__ __launch_bounds__(256) void k_hist(const int* __restrict__ ei32,
                                              const i64* __restrict__ ei64,
                                              const int* __restrict__ flag, int e,
                                              int nb, int* __restrict__ hist) {
  __shared__ int h[128];
  int c = blockIdx.x;
  int t = threadIdx.x;
  for (int i = t; i < nb; i += 256) h[i] = 0;
  __syncthreads();
  int is64 = *flag;
  long long base = (long long)c * CH;
  long long lim = base + CH < (long long)e ? base + CH : (long long)e;
  for (long long i = base + t; i < lim; i += 256) {
    int d = is64 ? (int)ei64[e + i] : ei32[e + i];
    atomicAdd(&h[d >> 9], 1);
  }
  __syncthreads();
  for (int i = t; i < nb; i += 256) hist[c * nb + i] = h[i];
}

// Pass B (1 block, LDS-resident): chunkoff[c][b] = bucketbase[b] + prefix_c(hist[:,b]).
// Requires nc*nb <= MAXHB and nb <= 128. Coalesced bulk load/store; serial chains in LDS.
__global__ __launch_bounds__(1024) void k_bscan(const int* __restrict__ hist,
                                                int nc, int nb,
                                                int* __restrict__ chunkoff,
                                                int* __restrict__ bucketbase) {
  __shared__ int h[MAXHB];
  __shared__ int tot[128];
  __shared__ int bb[129];
  int t = threadIdx.x;
  int total = nc * nb;
  for (int i = t; i < total; i += 1024) h[i] = hist[i];
  __syncthreads();
  if (t < nb) {  // bucket-local prefix over chunks, LDS-resident chain
    int run = 0;
    for (int c = 0; c < nc; ++c) {
      int v = h[c * nb + t];
      h[c * nb + t] = run;
      run += v;
    }
    tot[t] = run;
  }
  __syncthreads();
  if (t == 0) {  // exclusive scan of bucket totals (nb <= 128, LDS)
    int run = 0;
    for (int b = 0; b < nb; ++b) { bb[b] = run; run += tot[b]; }
    bb[nb] = run;
  }
  __syncthreads();
  for (int i = t; i < total; i += 1024) chunkoff[i] = h[i] + bb[i % nb];
  if (t <= nb) bucketbase[t] = bb[t];
}

// Pass B fallback (original, global-latency-bound) for sizes exceeding LDS.
__global__ __launch_bounds__(128) void k_bscan_slow(const int* __restrict__ hist,
                                                    int nc, int nb,
                                                    int* __restrict__ chunkoff,
                                                    int* __restrict__ bucketbase) {
  __shared__ int tot[129];
  int b = threadIdx.x;
  if (b < nb) {
    int s = 0;
    for (int c = 0; c < nc; ++c) s += hist[c * nb + b];
    tot[b] = s;
  }
  __syncthreads();
  if (b == 0) {
    int run = 0;
    for (int i = 0; i < nb; ++i) { int v = tot[i]; tot[i] = run; run += v; }
    tot[nb] = run;
  }
  __syncthreads();
  if (b < nb) {
    int off = tot[b];
    for (int c = 0; c < nc; ++c) {
      chunkoff[c * nb + b] = off;
      off += hist[c * nb + b];
    }
  }
  if (b <= nb) bucketbase[b] = tot[b];
}

// Pass C: bin edges into bucket-grouped (dstlow<<16 | src) u32 pairs.
// Each block's run per bucket is a private contiguous span -> full-line writes.
__global__ __launch_bounds__(256) void k_bin(const int* __restrict__ ei32,
                                             const i64* __restrict__ ei64,
                                             const int* __restrict__ flag, int e,
                                             int nb, const int* __restrict__ chunkoff,
                                             u32* __restrict__ pairs) {
  __shared__ int cur[128];
  int c = blockIdx.x;
  int t = threadIdx.x;
  for (int i = t; i < nb; i += 256) cur[i] = chunkoff[c * nb + i];
  __syncthreads();
  int is64 = *flag;
  long long base = (long long)c * CH;
  long long lim = base + CH < (long long)e ? base + CH : (long long)e;
  for (long long i = base + t; i < lim; i += 256) {
    int s, d;
    if (is64) { s = (int)ei64[i]; d = (int)ei64[e + i]; }
    else      { s = ei32[i];      d = ei32[e + i]; }
    int slot = atomicAdd(&cur[d >> 9], 1);
    pairs[slot] = ((u32)(d & (RPB - 1)) << 16) | (u32)(u16)s;
  }
}

// Pass D: one block per bucket. LDS count (-> dis, rowptr ends) + LDS scan +
// LDS-cursor scatter of u16 src into this block's private csr span.
__global__ __launch_bounds__(512) void k_csr(const u32* __restrict__ pairs,
                                             const int* __restrict__ bucketbase,
                                             int n, int* __restrict__ rowptr,
                                             float* __restrict__ dis,
                                             u16* __restrict__ csr_src) {
  __shared__ int cnts[512];
  __shared__ int sbuf[512];
  __shared__ int cur[512];
  int b = blockIdx.x;
  int t = threadIdx.x;
  int base = bucketbase[b];
  int end = bucketbase[b + 1];
  cnts[t] = 0;
  __syncthreads();
  for (int i = base + t; i < end; i += 512)
    atomicAdd(&cnts[pairs[i] >> 16], 1);
  __syncthreads();
  int c0 = cnts[t];
  sbuf[t] = c0;
  __syncthreads();
  for (int off = 1; off < 512; off <<= 1) {
    int v = (t >= off) ? sbuf[t - off] : 0;
    __syncthreads();
    sbuf[t] += v;
    __syncthreads();
  }
  int incl = sbuf[t];
  int gr = b * RPB + t;
  if (gr < n) {
    rowptr[gr] = base + incl;           // row END (globally consistent)
    dis[gr] = rsqrtf((float)(c0 + 1));  // deg includes self-loop
  }
  cur[t] = incl - c0;                    // bucket-local exclusive start
  __syncthreads();
  for (int i = base + t; i < end; i += 512) {
    u32 p = pairs[i];
    int slot = atomicAdd(&cur[p >> 16], 1);
    csr_src[base + slot] = (u16)(p & 0xFFFFu);
  }
}

// Ybf[n x 128](bf16) = X @ W, MFMA bf16, f32 accum. X f32 (XBF=0) or bf16 (XBF=1).
// Block tile 128x128, 4 waves x 32 rows. BN: relu(x*scale+shift) fused on load.
#define GR 128
#define LDK 136  // padded bf16 leading dim: 272B rows, 16B-aligned, 2-way banks (free)
template <bool BN, bool XBF>
__global__ __launch_bounds__(256) void k_gemm(const float* __restrict__ Xf,
                                              const u16* __restrict__ Xb,
                                              const float* __restrict__ W,
                                              u16* __restrict__ Ybf, int n,
                                              const float* __restrict__ scale,
                                              const float* __restrict__ shift) {
  __shared__ u16 Xl[GR * LDK];   // ~34 KB
  __shared__ u16 Wt[128 * LDK];  // ~34 KB
  int t = threadIdx.x;
  int row0 = blockIdx.x * GR;
  {  // stage Wt transposed (bf16)
    int kk = t >> 5;
    int c4 = (t & 31) << 2;
    for (int k = kk; k < 128; k += 8) {
      float4 w = *(const float4*)&W[k * D + c4];
      Wt[(c4 + 0) * LDK + k] = f2bf(w.x);
      Wt[(c4 + 1) * LDK + k] = f2bf(w.y);
      Wt[(c4 + 2) * LDK + k] = f2bf(w.z);
      Wt[(c4 + 3) * LDK + k] = f2bf(w.w);
    }
  }
  {  // stage Xl (bf16), optional BN+relu
    int r = t >> 5;
    int c4 = (t & 31) << 2;
    float4 sc, sh;
    if (BN) { sc = ((const float4*)scale)[t & 31]; sh = ((const float4*)shift)[t & 31]; }
    for (int rr = r; rr < GR; rr += 8) {
      int gr = row0 + rr;
      uint2 pk = {0u, 0u};
      if (gr < n) {
        if (XBF) {
          pk = *(const uint2*)&Xb[(size_t)gr * D + c4];
          if (BN) pk = pk4(bnrelu4(unpk4(pk), sc, sh));
        } else {
          float4 v = *(const float4*)&Xf[(size_t)gr * D + c4];
          if (BN) v = bnrelu4(v, sc, sh);
          pk = pk4(v);
        }
      }
      *(uint2*)&Xl[rr * LDK + c4] = pk;
    }
  }
  __syncthreads();
  int wv = t >> 6;
  int l = t & 63;
  int lg = l >> 4;
  int li = l & 15;
  int wr = wv * 32;
  f32x4 acc[2][8];
#pragma unroll
  for (int m = 0; m < 2; ++m)
#pragma unroll
    for (int nf = 0; nf < 8; ++nf)
      acc[m][nf] = (f32x4){0.f, 0.f, 0.f, 0.f};
#pragma unroll
  for (int ks = 0; ks < 4; ++ks) {
    int k0 = ks * 32 + lg * 8;
    bf16x8 a0 = *(const bf16x8*)&Xl[(wr + li) * LDK + k0];
    bf16x8 a1 = *(const bf16x8*)&Xl[(wr + 16 + li) * LDK + k0];
#pragma unroll
    for (int nf = 0; nf < 8; ++nf) {
      bf16x8 b = *(const bf16x8*)&Wt[(nf * 16 + li) * LDK + k0];
      acc[0][nf] = __builtin_amdgcn_mfma_f32_16x16x32_bf16(a0, b, acc[0][nf], 0, 0, 0);
      acc[1][nf] = __builtin_amdgcn_mfma_f32_16x16x32_bf16(a1, b, acc[1][nf], 0, 0, 0);
    }
  }
#pragma unroll
  for (int m = 0; m < 2; ++m) {
#pragma unroll
    for (int r = 0; r < 4; ++r) {
      int grow = row0 + wr + 16 * m + lg * 4 + r;
      if (grow < n) {
        u16* orow = Ybf + (size_t)grow * D;
#pragma unroll
        for (int nf = 0; nf < 8; ++nf)
          orow[nf * 16 + li] = f2bf(acc[m][nf][r]);
      }
    }
  }
}

// Pull-gather, one 32-lane group per dst row, grid-stride over rows.
// L2=false (layer1): out bf16 h1pre; accumulate BN col-stats -> block partials.
// L2=true  (layer2): skip = relu(BN(h1bf)) added; out f32 (final).
template <bool L2>
__global__ __launch_bounds__(256) void k_gather(const u16* __restrict__ feat,
                                                const u16* __restrict__ h1bf,
                                                const float* __restrict__ bias,
                                                const float* __restrict__ dis,
                                                const int* __restrict__ rowptr,
                                                const u16* __restrict__ csr_src,
                                                float* __restrict__ outf,
                                                u16* __restrict__ outb, int n,
                                                const float* __restrict__ scale,
                                                const float* __restrict__ shift,
                                                float* __restrict__ partial) {
  __shared__ float s_l[8][128];
  __shared__ float q_l[8][128];
  int t = threadIdx.x;
  int lane = t & 31;
  int g = t >> 5;
  int ngroups = gridDim.x * 8;
  float4 s4 = {0.f, 0.f, 0.f, 0.f};
  float4 q4 = {0.f, 0.f, 0.f, 0.f};
  float4 bv = ((const float4*)bias)[lane];
  float4 sc, sh;
  if (L2) { sc = ((const float4*)scale)[lane]; sh = ((const float4*)shift)[lane]; }
  for (int r = blockIdx.x * 8 + g; r < n; r += ngroups) {
    int start = (r == 0) ? 0 : rowptr[r - 1];
    int end = rowptr[r];
    float dr = dis[r];
    float4 acc = bv;
    float4 sv = ldbf4(feat, (size_t)r, lane);
    acc = fma4(dr * dr, sv, acc);
    if (L2) {
      float4 h = bnrelu4(ldbf4(h1bf, (size_t)r, lane), sc, sh);
      acc.x += h.x; acc.y += h.y; acc.z += h.z; acc.w += h.w;
    }
    float4 acc1 = {0.f, 0.f, 0.f, 0.f};
    int j = start;
    for (; j + 4 <= end; j += 4) {
      int s0 = csr_src[j];
      int s1 = csr_src[j + 1];
      int s2 = csr_src[j + 2];
      int s3 = csr_src[j + 3];
      float w0 = dis[s0] * dr;
      float w1 = dis[s1] * dr;
      float w2 = dis[s2] * dr;
      float w3 = dis[s3] * dr;
      float4 v0 = ldbf4(feat, (size_t)s0, lane);
      float4 v1 = ldbf4(feat, (size_t)s1, lane);
      float4 v2 = ldbf4(feat, (size_t)s2, lane);
      float4 v3 = ldbf4(feat, (size_t)s3, lane);
      acc = fma4(w0, v0, acc);
      acc1 = fma4(w1, v1, acc1);
      acc = fma4(w2, v2, acc);
      acc1 = fma4(w3, v3, acc1);
    }
    for (; j < end; ++j) {
      int s0 = csr_src[j];
      float w0 = dis[s0] * dr;
      acc = fma4(w0, ldbf4(feat, (size_t)s0, lane), acc);
    }
    acc.x += acc1.x; acc.y += acc1.y; acc.z += acc1.z; acc.w += acc1.w;
    if (L2) {
      ((float4*)(outf + (size_t)r * D))[lane] = acc;
    } else {
      *(uint2*)(outb + (size_t)r * D + lane * 4) = pk4(acc);
      s4.x += acc.x; s4.y += acc.y; s4.z += acc.z; s4.w += acc.w;
      q4.x = fmaf(acc.x, acc.x, q4.x);
      q4.y = fmaf(acc.y, acc.y, q4.y);
      q4.z = fmaf(acc.z, acc.z, q4.z);
      q4.w = fmaf(acc.w, acc.w, q4.w);
    }
  }
  if (!L2) {
    *(float4*)&s_l[g][lane * 4] = s4;
    *(float4*)&q_l[g][lane * 4] = q4;
    __syncthreads();
    float v = 0.f;
    if (t < 128) {
#pragma unroll
      for (int gg = 0; gg < 8; ++gg) v += s_l[gg][t];
    } else {
#pragma unroll
      for (int gg = 0; gg < 8; ++gg) v += q_l[gg][t - 128];
    }
    partial[blockIdx.x * 256 + t] = v;  // [0..127]=colsum, [128..255]=colsumsq
  }
}

// Fold block partials -> mu/var -> scale/shift. One block per column.
__global__ __launch_bounds__(256) void k_bnreduce(const float* __restrict__ partial,
                                                  int nbp,
                                                  const float* __restrict__ gamma,
                                                  const float* __restrict__ beta,
                                                  float* __restrict__ scale,
                                                  float* __restrict__ shift, int n) {
  __shared__ float rs[256], rq[256];
  int c = blockIdx.x;
  int t = threadIdx.x;
  float s = 0.f, q = 0.f;
  for (int b = t; b < nbp; b += 256) {
    s += partial[b * 256 + c];
    q += partial[b * 256 + 128 + c];
  }
  rs[t] = s; rq[t] = q;
  __syncthreads();
  for (int st = 128; st > 0; st >>= 1) {
    if (t < st) { rs[t] += rs[t + st]; rq[t] += rq[t + st]; }
    __syncthreads();
  }
  if (t == 0) {
    float inv_n = 1.0f / (float)n;
    float mu = rs[0] * inv_n;
    float var = rq[0] * inv_n - mu * mu;
    float sc = gamma[c] * rsqrtf(var + 1e-5f);
    scale[c] = sc;
    shift[c] = beta[c] - mu * sc;
  }
}

extern "C" void kernel_launch(void* const* d_in, const int* in_sizes, int n_in,
                              void* d_out, int out_size, void* d_ws, size_t ws_size,
                              hipStream_t stream) {
  const float* x     = (const float*)d_in[0];
  const int*   ei32  = (const int*)d_in[1];
  const i64*   ei64  = (const i64*)d_in[1];
  const float* W1    = (const float*)d_in[2];
  const float* b1    = (const float*)d_in[3];
  const float* W2    = (const float*)d_in[4];
  const float* b2    = (const float*)d_in[5];
  const float* gamma = (const float*)d_in[6];
  const float* beta  = (const float*)d_in[7];
  float* out = (float*)d_out;

  const int n = in_sizes[0] / D;  // 50000
  const int e = in_sizes[1] / 2;  // 800000
  const int GB1 = 1024;           // persistent gather1 blocks (stats partials)
  const int NB = (n + RPB - 1) / RPB;  // buckets (98)
  const int NC = (e + CH - 1) / CH;    // chunks (196)

  // Workspace layout (~30 MB)
  size_t npad = ((size_t)n + 255) & ~255ULL;
  size_t epad = ((size_t)e + 255) & ~255ULL;
  char* p = (char*)d_ws;
  float* dis      = (float*)p; p += npad * 4;
  int*   rowptr   = (int*)p;   p += npad * 4;
  u16*   csr16    = (u16*)p;   p += epad * 2;
  u32*   pairs    = (u32*)p;   p += epad * 4;
  int*   hist     = (int*)p;   p += (size_t)NC * NB * 4;
  int*   chunkoff = (int*)p;   p += (size_t)NC * NB * 4;
  int*   bucketbase = (int*)p; p += ((size_t)NB + 1 + 63) / 64 * 64 * 4;
  u16*   hwbf     = (u16*)p;   p += (size_t)n * D * 2;  // gemm out (hw1, then hw2)
  u16*   h1bf     = (u16*)p;   p += (size_t)n * D * 2;  // h1pre (bf16)
  float* partial  = (float*)p; p += (size_t)GB1 * 256 * 4;
  float* scale    = (float*)p; p += D * 4;
  float* shift    = (float*)p; p += D * 4;
  int*   flag     = (int*)p;   p += 256 * 4;

  int gb = (n + 7) / 8;          // gather2: 8 rows per 256-thread block
  int mb = (n + GR - 1) / GR;    // gemm: 128 rows per block

  // CSR build: atomic-free bucket sort (LDS-local randomness only)
  k_detect<<<1, 256, 0, stream>>>((const unsigned*)d_in[1], flag);
  k_hist<<<NC, 256, 0, stream>>>(ei32, ei64, flag, e, NB, hist);
  if (NC * NB <= MAXHB && NB <= 128)
    k_bscan<<<1, 1024, 0, stream>>>(hist, NC, NB, chunkoff, bucketbase);
  else
    k_bscan_slow<<<1, 128, 0, stream>>>(hist, NC, NB, chunkoff, bucketbase);
  k_bin<<<NC, 256, 0, stream>>>(ei32, ei64, flag, e, NB, chunkoff, pairs);
  k_csr<<<NB, 512, 0, stream>>>(pairs, bucketbase, n, rowptr, dis, csr16);

  // layer 1: conv (MFMA) -> gather (+fused BN stats) -> scale/shift
  k_gemm<false, false><<<mb, 256, 0, stream>>>(x, nullptr, W1, hwbf, n, nullptr, nullptr);
  k_gather<false><<<GB1, 256, 0, stream>>>(hwbf, nullptr, b1, dis, rowptr, csr16,
                                           nullptr, h1bf, n, nullptr, nullptr, partial);
  k_bnreduce<<<D, 256, 0, stream>>>(partial, GB1, gamma, beta, scale, shift, n);

  // layer 2: conv (BN+relu fused, bf16 in) + gather with fused BN'd skip
  k_gemm<true, true><<<mb, 256, 0, stream>>>(nullptr, h1bf, W2, hwbf, n, scale, shift);
  k_gather<true><<<gb, 256, 0, stream>>>(hwbf, h1bf, b2, dis, rowptr, csr16,
                                         out, nullptr, n, scale, shift, nullptr);
}

// Round 12
// 256.486 us; speedup vs baseline: 1.2472x; 1.0265x over previous
//
#include <hip/hip_runtime.h>

#define D 128
typedef long long i64;
typedef unsigned short u16;
typedef unsigned int u32;
typedef __attribute__((ext_vector_type(8))) short bf16x8;
typedef __attribute__((ext_vector_type(4))) float f32x4;

#define RPB 512    // rows per bucket (dst >> 9)
#define CH 4096    // edges per chunk for hist/bin
#define MAXHB 19712  // max NC*NB ints LDS-resident in k_bscan (~77 KB)

__device__ inline float4 fma4(float a, float4 b, float4 c) {
  c.x = fmaf(a, b.x, c.x);
  c.y = fmaf(a, b.y, c.y);
  c.z = fmaf(a, b.z, c.z);
  c.w = fmaf(a, b.w, c.w);
  return c;
}

__device__ inline float4 bnrelu4(float4 v, float4 sc, float4 sh) {
  v.x = fmaxf(fmaf(v.x, sc.x, sh.x), 0.f);
  v.y = fmaxf(fmaf(v.y, sc.y, sh.y), 0.f);
  v.z = fmaxf(fmaf(v.z, sc.z, sh.z), 0.f);
  v.w = fmaxf(fmaf(v.w, sc.w, sh.w), 0.f);
  return v;
}

__device__ inline u16 f2bf(float f) {  // RNE f32->bf16
  union { float f; u32 u; } v; v.f = f;
  u32 r = (v.u + 0x7FFFu + ((v.u >> 16) & 1u)) >> 16;
  return (u16)r;
}

__device__ inline uint2 pk4(float4 v) {
  uint2 p;
  p.x = (u32)f2bf(v.x) | ((u32)f2bf(v.y) << 16);
  p.y = (u32)f2bf(v.z) | ((u32)f2bf(v.w) << 16);
  return p;
}

__device__ inline float4 unpk4(uint2 p) {
  float4 v;
  v.x = __uint_as_float(p.x << 16);
  v.y = __uint_as_float(p.x & 0xFFFF0000u);
  v.z = __uint_as_float(p.y << 16);
  v.w = __uint_as_float(p.y & 0xFFFF0000u);
  return v;
}

__device__ inline float4 ldbf4(const u16* __restrict__ feat, size_t row, int lane) {
  return unpk4(*(const uint2*)(feat + row * D + lane * 4));
}

// Detect int64-vs-int32 edge_index (odd u32 words all zero for int64 < 2^32).
__global__ void k_detect(const unsigned* __restrict__ w, int* __restrict__ flag) {
  __shared__ unsigned red[256];
  unsigned v = 0;
  for (int i = threadIdx.x; i < 2048; i += 256) v |= w[2 * i + 1];
  red[threadIdx.x] = v;
  __syncthreads();
  for (int s = 128; s > 0; s >>= 1) {
    if ((int)threadIdx.x < s) red[threadIdx.x] |= red[threadIdx.x + s];
    __syncthreads();
  }
  if (threadIdx.x == 0) *flag = (red[0] == 0u) ? 1 : 0;
}

// Pass A: per-chunk per-bucket histogram of dst. LDS atomics only.
__global__ __launch_bounds__(256) void k_hist(const int* __restrict__ ei32,
                                              const i64* __restrict__ ei64,
                                              const int* __restrict__ flag, int e,
                                              int nb, int* __restrict__ hist) {
  __shared__ int h[128];
  int c = blockIdx.x;
  int t = threadIdx.x;
  for (int i = t; i < nb; i += 256) h[i] = 0;
  __syncthreads();
  int is64 = *flag;
  long long base = (long long)c * CH;
  long long lim = base + CH < (long long)e ? base + CH : (long long)e;
  for (long long i = base + t; i < lim; i += 256) {
    int d = is64 ? (int)ei64[e + i] : ei32[e + i];
    atomicAdd(&h[d >> 9], 1);
  }
  __syncthreads();
  for (int i = t; i < nb; i += 256) hist[c * nb + i] = h[i];
}

// Pass B (1 block, LDS-resident): chunkoff[c][b] = bucketbase[b] + prefix_c(hist[:,b]).
__global__ __launch_bounds__(1024) void k_bscan(const int* __restrict__ hist,
                                                int nc, int nb,
                                                int* __restrict__ chunkoff,
                                                int* __restrict__ bucketbase) {
  __shared__ int h[MAXHB];
  __shared__ int tot[128];
  __shared__ int bb[129];
  int t = threadIdx.x;
  int total = nc * nb;
  for (int i = t; i < total; i += 1024) h[i] = hist[i];
  __syncthreads();
  if (t < nb) {  // bucket-local prefix over chunks, LDS-resident chain
    int run = 0;
    for (int c = 0; c < nc; ++c) {
      int v = h[c * nb + t];
      h[c * nb + t] = run;
      run += v;
    }
    tot[t] = run;
  }
  __syncthreads();
  if (t == 0) {
    int run = 0;
    for (int b = 0; b < nb; ++b) { bb[b] = run; run += tot[b]; }
    bb[nb] = run;
  }
  __syncthreads();
  for (int i = t; i < total; i += 1024) chunkoff[i] = h[i] + bb[i % nb];
  if (t <= nb) bucketbase[t] = bb[t];
}

// Pass B fallback (global-latency-bound) for sizes exceeding LDS.
__global__ __launch_bounds__(128) void k_bscan_slow(const int* __restrict__ hist,
                                                    int nc, int nb,
                                                    int* __restrict__ chunkoff,
                                                    int* __restrict__ bucketbase) {
  __shared__ int tot[129];
  int b = threadIdx.x;
  if (b < nb) {
    int s = 0;
    for (int c = 0; c < nc; ++c) s += hist[c * nb + b];
    tot[b] = s;
  }
  __syncthreads();
  if (b == 0) {
    int run = 0;
    for (int i = 0; i < nb; ++i) { int v = tot[i]; tot[i] = run; run += v; }
    tot[nb] = run;
  }
  __syncthreads();
  if (b < nb) {
    int off = tot[b];
    for (int c = 0; c < nc; ++c) {
      chunkoff[c * nb + b] = off;
      off += hist[c * nb + b];
    }
  }
  if (b <= nb) bucketbase[b] = tot[b];
}

// Pass C: bin edges into bucket-grouped (dstlow<<16 | src) u32 pairs.
__global__ __launch_bounds__(256) void k_bin(const int* __restrict__ ei32,
                                             const i64* __restrict__ ei64,
                                             const int* __restrict__ flag, int e,
                                             int nb, const int* __restrict__ chunkoff,
                                             u32* __restrict__ pairs) {
  __shared__ int cur[128];
  int c = blockIdx.x;
  int t = threadIdx.x;
  for (int i = t; i < nb; i += 256) cur[i] = chunkoff[c * nb + i];
  __syncthreads();
  int is64 = *flag;
  long long base = (long long)c * CH;
  long long lim = base + CH < (long long)e ? base + CH : (long long)e;
  for (long long i = base + t; i < lim; i += 256) {
    int s, d;
    if (is64) { s = (int)ei64[i]; d = (int)ei64[e + i]; }
    else      { s = ei32[i];      d = ei32[e + i]; }
    int slot = atomicAdd(&cur[d >> 9], 1);
    pairs[slot] = ((u32)(d & (RPB - 1)) << 16) | (u32)(u16)s;
  }
}

// Pass D: one block per bucket. LDS count (-> dis, rowptr ends) + LDS scan +
// LDS-cursor scatter of u16 src into this block's private csr span.
__global__ __launch_bounds__(512) void k_csr(const u32* __restrict__ pairs,
                                             const int* __restrict__ bucketbase,
                                             int n, int* __restrict__ rowptr,
                                             float* __restrict__ dis,
                                             u16* __restrict__ csr_src) {
  __shared__ int cnts[512];
  __shared__ int sbuf[512];
  __shared__ int cur[512];
  int b = blockIdx.x;
  int t = threadIdx.x;
  int base = bucketbase[b];
  int end = bucketbase[b + 1];
  cnts[t] = 0;
  __syncthreads();
  for (int i = base + t; i < end; i += 512)
    atomicAdd(&cnts[pairs[i] >> 16], 1);
  __syncthreads();
  int c0 = cnts[t];
  sbuf[t] = c0;
  __syncthreads();
  for (int off = 1; off < 512; off <<= 1) {
    int v = (t >= off) ? sbuf[t - off] : 0;
    __syncthreads();
    sbuf[t] += v;
    __syncthreads();
  }
  int incl = sbuf[t];
  int gr = b * RPB + t;
  if (gr < n) {
    rowptr[gr] = base + incl;           // row END (globally consistent)
    dis[gr] = rsqrtf((float)(c0 + 1));  // deg includes self-loop
  }
  cur[t] = incl - c0;                    // bucket-local exclusive start
  __syncthreads();
  for (int i = base + t; i < end; i += 512) {
    u32 p = pairs[i];
    int slot = atomicAdd(&cur[p >> 16], 1);
    csr_src[base + slot] = (u16)(p & 0xFFFFu);
  }
}

// Ybf[n x 128](bf16) = X @ W, MFMA bf16, f32 accum. X f32 (XBF=0) or bf16 (XBF=1).
// Block tile 128x128, 4 waves x 32 rows. BN: relu(x*scale+shift) fused on load.
#define GR 128
#define LDK 136  // padded bf16 leading dim: 272B rows, 16B-aligned, 2-way banks (free)
template <bool BN, bool XBF>
__global__ __launch_bounds__(256) void k_gemm(const float* __restrict__ Xf,
                                              const u16* __restrict__ Xb,
                                              const float* __restrict__ W,
                                              u16* __restrict__ Ybf, int n,
                                              const float* __restrict__ scale,
                                              const float* __restrict__ shift) {
  __shared__ u16 Xl[GR * LDK];   // ~34 KB
  __shared__ u16 Wt[128 * LDK];  // ~34 KB
  int t = threadIdx.x;
  int row0 = blockIdx.x * GR;
  {  // stage Wt transposed (bf16)
    int kk = t >> 5;
    int c4 = (t & 31) << 2;
    for (int k = kk; k < 128; k += 8) {
      float4 w = *(const float4*)&W[k * D + c4];
      Wt[(c4 + 0) * LDK + k] = f2bf(w.x);
      Wt[(c4 + 1) * LDK + k] = f2bf(w.y);
      Wt[(c4 + 2) * LDK + k] = f2bf(w.z);
      Wt[(c4 + 3) * LDK + k] = f2bf(w.w);
    }
  }
  {  // stage Xl (bf16), optional BN+relu
    int r = t >> 5;
    int c4 = (t & 31) << 2;
    float4 sc, sh;
    if (BN) { sc = ((const float4*)scale)[t & 31]; sh = ((const float4*)shift)[t & 31]; }
    for (int rr = r; rr < GR; rr += 8) {
      int gr = row0 + rr;
      uint2 pk = {0u, 0u};
      if (gr < n) {
        if (XBF) {
          pk = *(const uint2*)&Xb[(size_t)gr * D + c4];
          if (BN) pk = pk4(bnrelu4(unpk4(pk), sc, sh));
        } else {
          float4 v = *(const float4*)&Xf[(size_t)gr * D + c4];
          if (BN) v = bnrelu4(v, sc, sh);
          pk = pk4(v);
        }
      }
      *(uint2*)&Xl[rr * LDK + c4] = pk;
    }
  }
  __syncthreads();
  int wv = t >> 6;
  int l = t & 63;
  int lg = l >> 4;
  int li = l & 15;
  int wr = wv * 32;
  f32x4 acc[2][8];
#pragma unroll
  for (int m = 0; m < 2; ++m)
#pragma unroll
    for (int nf = 0; nf < 8; ++nf)
      acc[m][nf] = (f32x4){0.f, 0.f, 0.f, 0.f};
#pragma unroll
  for (int ks = 0; ks < 4; ++ks) {
    int k0 = ks * 32 + lg * 8;
    bf16x8 a0 = *(const bf16x8*)&Xl[(wr + li) * LDK + k0];
    bf16x8 a1 = *(const bf16x8*)&Xl[(wr + 16 + li) * LDK + k0];
#pragma unroll
    for (int nf = 0; nf < 8; ++nf) {
      bf16x8 b = *(const bf16x8*)&Wt[(nf * 16 + li) * LDK + k0];
      acc[0][nf] = __builtin_amdgcn_mfma_f32_16x16x32_bf16(a0, b, acc[0][nf], 0, 0, 0);
      acc[1][nf] = __builtin_amdgcn_mfma_f32_16x16x32_bf16(a1, b, acc[1][nf], 0, 0, 0);
    }
  }
#pragma unroll
  for (int m = 0; m < 2; ++m) {
#pragma unroll
    for (int r = 0; r < 4; ++r) {
      int grow = row0 + wr + 16 * m + lg * 4 + r;
      if (grow < n) {
        u16* orow = Ybf + (size_t)grow * D;
#pragma unroll
        for (int nf = 0; nf < 8; ++nf)
          orow[nf * 16 + li] = f2bf(acc[m][nf][r]);
      }
    }
  }
}

// Pull-gather, one 32-lane group per dst row, grid-stride over rows.
// Edge loop: 8-edge window with prefetched indices+weights, two 4-deep
// feat-load batches into 4 accumulators (idx->feat serial chain broken).
// L2=false (layer1): out bf16 h1pre; accumulate BN col-stats -> block partials.
// L2=true  (layer2): skip = relu(BN(h1bf)) added; out f32 (final).
template <bool L2>
__global__ __launch_bounds__(256) void k_gather(const u16* __restrict__ feat,
                                                const u16* __restrict__ h1bf,
                                                const float* __restrict__ bias,
                                                const float* __restrict__ dis,
                                                const int* __restrict__ rowptr,
                                                const u16* __restrict__ csr_src,
                                                float* __restrict__ outf,
                                                u16* __restrict__ outb, int n,
                                                const float* __restrict__ scale,
                                                const float* __restrict__ shift,
                                                float* __restrict__ partial) {
  __shared__ float s_l[8][128];
  __shared__ float q_l[8][128];
  int t = threadIdx.x;
  int lane = t & 31;
  int g = t >> 5;
  int ngroups = gridDim.x * 8;
  float4 s4 = {0.f, 0.f, 0.f, 0.f};
  float4 q4 = {0.f, 0.f, 0.f, 0.f};
  float4 bv = ((const float4*)bias)[lane];
  float4 sc, sh;
  if (L2) { sc = ((const float4*)scale)[lane]; sh = ((const float4*)shift)[lane]; }
  for (int r = blockIdx.x * 8 + g; r < n; r += ngroups) {
    int start = (r == 0) ? 0 : rowptr[r - 1];
    int end = rowptr[r];
    float dr = dis[r];
    float4 acc = bv;
    float4 sv = ldbf4(feat, (size_t)r, lane);
    acc = fma4(dr * dr, sv, acc);
    if (L2) {
      float4 h = bnrelu4(ldbf4(h1bf, (size_t)r, lane), sc, sh);
      acc.x += h.x; acc.y += h.y; acc.z += h.z; acc.w += h.w;
    }
    float4 acc1 = {0.f, 0.f, 0.f, 0.f};
    float4 acc2 = {0.f, 0.f, 0.f, 0.f};
    float4 acc3 = {0.f, 0.f, 0.f, 0.f};
    int j = start;
    for (; j + 8 <= end; j += 8) {
      // prefetch 8 indices + 8 weights (breaks idx->feat dependence)
      int s0 = csr_src[j];
      int s1 = csr_src[j + 1];
      int s2 = csr_src[j + 2];
      int s3 = csr_src[j + 3];
      int s4i = csr_src[j + 4];
      int s5 = csr_src[j + 5];
      int s6 = csr_src[j + 6];
      int s7 = csr_src[j + 7];
      float w0 = dis[s0] * dr;
      float w1 = dis[s1] * dr;
      float w2 = dis[s2] * dr;
      float w3 = dis[s3] * dr;
      float w4 = dis[s4i] * dr;
      float w5 = dis[s5] * dr;
      float w6 = dis[s6] * dr;
      float w7 = dis[s7] * dr;
      // batch 1: 4 feat rows in flight
      float4 v0 = ldbf4(feat, (size_t)s0, lane);
      float4 v1 = ldbf4(feat, (size_t)s1, lane);
      float4 v2 = ldbf4(feat, (size_t)s2, lane);
      float4 v3 = ldbf4(feat, (size_t)s3, lane);
      acc = fma4(w0, v0, acc);
      acc1 = fma4(w1, v1, acc1);
      acc2 = fma4(w2, v2, acc2);
      acc3 = fma4(w3, v3, acc3);
      // batch 2 (reuses v registers)
      v0 = ldbf4(feat, (size_t)s4i, lane);
      v1 = ldbf4(feat, (size_t)s5, lane);
      v2 = ldbf4(feat, (size_t)s6, lane);
      v3 = ldbf4(feat, (size_t)s7, lane);
      acc = fma4(w4, v0, acc);
      acc1 = fma4(w5, v1, acc1);
      acc2 = fma4(w6, v2, acc2);
      acc3 = fma4(w7, v3, acc3);
    }
    for (; j + 2 <= end; j += 2) {
      int s0 = csr_src[j];
      int s1 = csr_src[j + 1];
      float w0 = dis[s0] * dr;
      float w1 = dis[s1] * dr;
      float4 v0 = ldbf4(feat, (size_t)s0, lane);
      float4 v1 = ldbf4(feat, (size_t)s1, lane);
      acc = fma4(w0, v0, acc);
      acc1 = fma4(w1, v1, acc1);
    }
    if (j < end) {
      int s0 = csr_src[j];
      float w0 = dis[s0] * dr;
      acc = fma4(w0, ldbf4(feat, (size_t)s0, lane), acc);
    }
    acc.x += acc1.x + acc2.x + acc3.x;
    acc.y += acc1.y + acc2.y + acc3.y;
    acc.z += acc1.z + acc2.z + acc3.z;
    acc.w += acc1.w + acc2.w + acc3.w;
    if (L2) {
      ((float4*)(outf + (size_t)r * D))[lane] = acc;
    } else {
      *(uint2*)(outb + (size_t)r * D + lane * 4) = pk4(acc);
      s4.x += acc.x; s4.y += acc.y; s4.z += acc.z; s4.w += acc.w;
      q4.x = fmaf(acc.x, acc.x, q4.x);
      q4.y = fmaf(acc.y, acc.y, q4.y);
      q4.z = fmaf(acc.z, acc.z, q4.z);
      q4.w = fmaf(acc.w, acc.w, q4.w);
    }
  }
  if (!L2) {
    *(float4*)&s_l[g][lane * 4] = s4;
    *(float4*)&q_l[g][lane * 4] = q4;
    __syncthreads();
    float v = 0.f;
    if (t < 128) {
#pragma unroll
      for (int gg = 0; gg < 8; ++gg) v += s_l[gg][t];
    } else {
#pragma unroll
      for (int gg = 0; gg < 8; ++gg) v += q_l[gg][t - 128];
    }
    partial[blockIdx.x * 256 + t] = v;  // [0..127]=colsum, [128..255]=colsumsq
  }
}

// Fold block partials -> mu/var -> scale/shift. One block per column.
__global__ __launch_bounds__(256) void k_bnreduce(const float* __restrict__ partial,
                                                  int nbp,
                                                  const float* __restrict__ gamma,
                                                  const float* __restrict__ beta,
                                                  float* __restrict__ scale,
                                                  float* __restrict__ shift, int n) {
  __shared__ float rs[256], rq[256];
  int c = blockIdx.x;
  int t = threadIdx.x;
  float s = 0.f, q = 0.f;
  for (int b = t; b < nbp; b += 256) {
    s += partial[b * 256 + c];
    q += partial[b * 256 + 128 + c];
  }
  rs[t] = s; rq[t] = q;
  __syncthreads();
  for (int st = 128; st > 0; st >>= 1) {
    if (t < st) { rs[t] += rs[t + st]; rq[t] += rq[t + st]; }
    __syncthreads();
  }
  if (t == 0) {
    float inv_n = 1.0f / (float)n;
    float mu = rs[0] * inv_n;
    float var = rq[0] * inv_n - mu * mu;
    float sc = gamma[c] * rsqrtf(var + 1e-5f);
    scale[c] = sc;
    shift[c] = beta[c] - mu * sc;
  }
}

extern "C" void kernel_launch(void* const* d_in, const int* in_sizes, int n_in,
                              void* d_out, int out_size, void* d_ws, size_t ws_size,
                              hipStream_t stream) {
  const float* x     = (const float*)d_in[0];
  const int*   ei32  = (const int*)d_in[1];
  const i64*   ei64  = (const i64*)d_in[1];
  const float* W1    = (const float*)d_in[2];
  const float* b1    = (const float*)d_in[3];
  const float* W2    = (const float*)d_in[4];
  const float* b2    = (const float*)d_in[5];
  const float* gamma = (const float*)d_in[6];
  const float* beta  = (const float*)d_in[7];
  float* out = (float*)d_out;

  const int n = in_sizes[0] / D;  // 50000
  const int e = in_sizes[1] / 2;  // 800000
  const int GB1 = 2048;           // persistent gather1 blocks: 8/CU -> 100% occup
  const int NB = (n + RPB - 1) / RPB;  // buckets (98)
  const int NC = (e + CH - 1) / CH;    // chunks (196)

  // Workspace layout (~31 MB)
  size_t npad = ((size_t)n + 255) & ~255ULL;
  size_t epad = ((size_t)e + 255) & ~255ULL;
  char* p = (char*)d_ws;
  float* dis      = (float*)p; p += npad * 4;
  int*   rowptr   = (int*)p;   p += npad * 4;
  u16*   csr16    = (u16*)p;   p += epad * 2;
  u32*   pairs    = (u32*)p;   p += epad * 4;
  int*   hist     = (int*)p;   p += (size_t)NC * NB * 4;
  int*   chunkoff = (int*)p;   p += (size_t)NC * NB * 4;
  int*   bucketbase = (int*)p; p += ((size_t)NB + 1 + 63) / 64 * 64 * 4;
  u16*   hwbf     = (u16*)p;   p += (size_t)n * D * 2;  // gemm out (hw1, then hw2)
  u16*   h1bf     = (u16*)p;   p += (size_t)n * D * 2;  // h1pre (bf16)
  float* partial  = (float*)p; p += (size_t)GB1 * 256 * 4;
  float* scale    = (float*)p; p += D * 4;
  float* shift    = (float*)p; p += D * 4;
  int*   flag     = (int*)p;   p += 256 * 4;

  int gb = (n + 7) / 8;          // gather2: 8 rows per 256-thread block
  int mb = (n + GR - 1) / GR;    // gemm: 128 rows per block

  // CSR build: atomic-free bucket sort (LDS-local randomness only)
  k_detect<<<1, 256, 0, stream>>>((const unsigned*)d_in[1], flag);
  k_hist<<<NC, 256, 0, stream>>>(ei32, ei64, flag, e, NB, hist);
  if (NC * NB <= MAXHB && NB <= 128)
    k_bscan<<<1, 1024, 0, stream>>>(hist, NC, NB, chunkoff, bucketbase);
  else
    k_bscan_slow<<<1, 128, 0, stream>>>(hist, NC, NB, chunkoff, bucketbase);
  k_bin<<<NC, 256, 0, stream>>>(ei32, ei64, flag, e, NB, chunkoff, pairs);
  k_csr<<<NB, 512, 0, stream>>>(pairs, bucketbase, n, rowptr, dis, csr16);

  // layer 1: conv (MFMA) -> gather (+fused BN stats) -> scale/shift
  k_gemm<false, false><<<mb, 256, 0, stream>>>(x, nullptr, W1, hwbf, n, nullptr, nullptr);
  k_gather<false><<<GB1, 256, 0, stream>>>(hwbf, nullptr, b1, dis, rowptr, csr16,
                                           nullptr, h1bf, n, nullptr, nullptr, partial);
  k_bnreduce<<<D, 256, 0, stream>>>(partial, GB1, gamma, beta, scale, shift, n);

  // layer 2: conv (BN+relu fused, bf16 in) + gather with fused BN'd skip
  k_gemm<true, true><<<mb, 256, 0, stream>>>(nullptr, h1bf, W2, hwbf, n, scale, shift);
  k_gather<true><<<gb, 256, 0, stream>>>(hwbf, h1bf, b2, dis, rowptr, csr16,
                                         out, nullptr, n, scale, shift, nullptr);
}

// Round 13
// 248.279 us; speedup vs baseline: 1.2885x; 1.0331x over previous
//
#include <hip/hip_runtime.h>

#define D 128
typedef long long i64;
typedef unsigned short u16;
typedef unsigned int u32;
typedef __attribute__((ext_vector_type(8))) short bf16x8;
typedef __attribute__((ext_vector_type(4))) float f32x4;

#define RPB 512    // rows per bucket (dst >> 9)
#define CH 4096    // edges per chunk for hist/bin
#define MAXHB 19712  // max NC*NB ints LDS-resident in k_bscan (~77 KB)

__device__ inline float4 fma4(float a, float4 b, float4 c) {
  c.x = fmaf(a, b.x, c.x);
  c.y = fmaf(a, b.y, c.y);
  c.z = fmaf(a, b.z, c.z);
  c.w = fmaf(a, b.w, c.w);
  return c;
}

__device__ inline float4 bnrelu4(float4 v, float4 sc, float4 sh) {
  v.x = fmaxf(fmaf(v.x, sc.x, sh.x), 0.f);
  v.y = fmaxf(fmaf(v.y, sc.y, sh.y), 0.f);
  v.z = fmaxf(fmaf(v.z, sc.z, sh.z), 0.f);
  v.w = fmaxf(fmaf(v.w, sc.w, sh.w), 0.f);
  return v;
}

__device__ inline u16 f2bf(float f) {  // RNE f32->bf16
  union { float f; u32 u; } v; v.f = f;
  u32 r = (v.u + 0x7FFFu + ((v.u >> 16) & 1u)) >> 16;
  return (u16)r;
}

__device__ inline uint2 pk4(float4 v) {
  uint2 p;
  p.x = (u32)f2bf(v.x) | ((u32)f2bf(v.y) << 16);
  p.y = (u32)f2bf(v.z) | ((u32)f2bf(v.w) << 16);
  return p;
}

__device__ inline float4 unpk4(uint2 p) {
  float4 v;
  v.x = __uint_as_float(p.x << 16);
  v.y = __uint_as_float(p.x & 0xFFFF0000u);
  v.z = __uint_as_float(p.y << 16);
  v.w = __uint_as_float(p.y & 0xFFFF0000u);
  return v;
}

__device__ inline float4 ldbf4(const u16* __restrict__ feat, size_t row, int lane) {
  return unpk4(*(const uint2*)(feat + row * D + lane * 4));
}

// Detect int64-vs-int32 edge_index (odd u32 words all zero for int64 < 2^32).
__global__ void k_detect(const unsigned* __restrict__ w, int* __restrict__ flag) {
  __shared__ unsigned red[256];
  unsigned v = 0;
  for (int i = threadIdx.x; i < 2048; i += 256) v |= w[2 * i + 1];
  red[threadIdx.x] = v;
  __syncthreads();
  for (int s = 128; s > 0; s >>= 1) {
    if ((int)threadIdx.x < s) red[threadIdx.x] |= red[threadIdx.x + s];
    __syncthreads();
  }
  if (threadIdx.x == 0) *flag = (red[0] == 0u) ? 1 : 0;
}

// Pass A: per-chunk per-bucket histogram of dst. LDS atomics only.
__global__ __launch_bounds__(256) void k_hist(const int* __restrict__ ei32,
                                              const i64* __restrict__ ei64,
                                              const int* __restrict__ flag, int e,
                                              int nb, int* __restrict__ hist) {
  __shared__ int h[128];
  int c = blockIdx.x;
  int t = threadIdx.x;
  for (int i = t; i < nb; i += 256) h[i] = 0;
  __syncthreads();
  int is64 = *flag;
  long long base = (long long)c * CH;
  long long lim = base + CH < (long long)e ? base + CH : (long long)e;
  for (long long i = base + t; i < lim; i += 256) {
    int d = is64 ? (int)ei64[e + i] : ei32[e + i];
    atomicAdd(&h[d >> 9], 1);
  }
  __syncthreads();
  for (int i = t; i < nb; i += 256) hist[c * nb + i] = h[i];
}

// Pass B (1 block, LDS-resident): chunkoff[c][b] = bucketbase[b] + prefix_c(hist[:,b]).
__global__ __launch_bounds__(1024) void k_bscan(const int* __restrict__ hist,
                                                int nc, int nb,
                                                int* __restrict__ chunkoff,
                                                int* __restrict__ bucketbase) {
  __shared__ int h[MAXHB];
  __shared__ int tot[128];
  __shared__ int bb[129];
  int t = threadIdx.x;
  int total = nc * nb;
  for (int i = t; i < total; i += 1024) h[i] = hist[i];
  __syncthreads();
  if (t < nb) {  // bucket-local prefix over chunks, LDS-resident chain
    int run = 0;
    for (int c = 0; c < nc; ++c) {
      int v = h[c * nb + t];
      h[c * nb + t] = run;
      run += v;
    }
    tot[t] = run;
  }
  __syncthreads();
  if (t == 0) {
    int run = 0;
    for (int b = 0; b < nb; ++b) { bb[b] = run; run += tot[b]; }
    bb[nb] = run;
  }
  __syncthreads();
  for (int i = t; i < total; i += 1024) chunkoff[i] = h[i] + bb[i % nb];
  if (t <= nb) bucketbase[t] = bb[t];
}

// Pass B fallback (global-latency-bound) for sizes exceeding LDS.
__global__ __launch_bounds__(128) void k_bscan_slow(const int* __restrict__ hist,
                                                    int nc, int nb,
                                                    int* __restrict__ chunkoff,
                                                    int* __restrict__ bucketbase) {
  __shared__ int tot[129];
  int b = threadIdx.x;
  if (b < nb) {
    int s = 0;
    for (int c = 0; c < nc; ++c) s += hist[c * nb + b];
    tot[b] = s;
  }
  __syncthreads();
  if (b == 0) {
    int run = 0;
    for (int i = 0; i < nb; ++i) { int v = tot[i]; tot[i] = run; run += v; }
    tot[nb] = run;
  }
  __syncthreads();
  if (b < nb) {
    int off = tot[b];
    for (int c = 0; c < nc; ++c) {
      chunkoff[c * nb + b] = off;
      off += hist[c * nb + b];
    }
  }
  if (b <= nb) bucketbase[b] = tot[b];
}

// Pass C: bin edges into bucket-grouped (dstlow<<16 | src) u32 pairs.
__global__ __launch_bounds__(256) void k_bin(const int* __restrict__ ei32,
                                             const i64* __restrict__ ei64,
                                             const int* __restrict__ flag, int e,
                                             int nb, const int* __restrict__ chunkoff,
                                             u32* __restrict__ pairs) {
  __shared__ int cur[128];
  int c = blockIdx.x;
  int t = threadIdx.x;
  for (int i = t; i < nb; i += 256) cur[i] = chunkoff[c * nb + i];
  __syncthreads();
  int is64 = *flag;
  long long base = (long long)c * CH;
  long long lim = base + CH < (long long)e ? base + CH : (long long)e;
  for (long long i = base + t; i < lim; i += 256) {
    int s, d;
    if (is64) { s = (int)ei64[i]; d = (int)ei64[e + i]; }
    else      { s = ei32[i];      d = ei32[e + i]; }
    int slot = atomicAdd(&cur[d >> 9], 1);
    pairs[slot] = ((u32)(d & (RPB - 1)) << 16) | (u32)(u16)s;
  }
}

// Pass D: one block per bucket. LDS count (-> dis, rowptr ends) + LDS scan +
// LDS-cursor scatter of u16 src into this block's private csr span.
__global__ __launch_bounds__(512) void k_csr(const u32* __restrict__ pairs,
                                             const int* __restrict__ bucketbase,
                                             int n, int* __restrict__ rowptr,
                                             float* __restrict__ dis,
                                             u16* __restrict__ csr_src) {
  __shared__ int cnts[512];
  __shared__ int sbuf[512];
  __shared__ int cur[512];
  int b = blockIdx.x;
  int t = threadIdx.x;
  int base = bucketbase[b];
  int end = bucketbase[b + 1];
  cnts[t] = 0;
  __syncthreads();
  for (int i = base + t; i < end; i += 512)
    atomicAdd(&cnts[pairs[i] >> 16], 1);
  __syncthreads();
  int c0 = cnts[t];
  sbuf[t] = c0;
  __syncthreads();
  for (int off = 1; off < 512; off <<= 1) {
    int v = (t >= off) ? sbuf[t - off] : 0;
    __syncthreads();
    sbuf[t] += v;
    __syncthreads();
  }
  int incl = sbuf[t];
  int gr = b * RPB + t;
  if (gr < n) {
    rowptr[gr] = base + incl;           // row END (globally consistent)
    dis[gr] = rsqrtf((float)(c0 + 1));  // deg includes self-loop
  }
  cur[t] = incl - c0;                    // bucket-local exclusive start
  __syncthreads();
  for (int i = base + t; i < end; i += 512) {
    u32 p = pairs[i];
    int slot = atomicAdd(&cur[p >> 16], 1);
    csr_src[base + slot] = (u16)(p & 0xFFFFu);
  }
}

// Ybf[n x 128](bf16) = X @ W, MFMA bf16, f32 accum. X f32 (XBF=0) or bf16 (XBF=1).
// Block tile 128x128, 4 waves x 32 rows. BN: relu(x*scale+shift) fused on load.
// Epilogue: fragments -> LDS repack (bf16) -> coalesced uint4 global stores.
#define GR 128
#define LDK 136  // padded bf16 leading dim: 272B rows (16B-mult), 2-way banks
template <bool BN, bool XBF>
__global__ __launch_bounds__(256) void k_gemm(const float* __restrict__ Xf,
                                              const u16* __restrict__ Xb,
                                              const float* __restrict__ W,
                                              u16* __restrict__ Ybf, int n,
                                              const float* __restrict__ scale,
                                              const float* __restrict__ shift) {
  __shared__ u16 Xl[GR * LDK];   // X tile [row][k]; reused for C repack
  __shared__ u16 Wt[128 * LDK];  // W^T [col][k]
  int t = threadIdx.x;
  int row0 = blockIdx.x * GR;
  {  // stage Wt transposed: pack k-pairs in regs, 2x ds_write_b128 per col
    int kk = t >> 5;            // 0..7 -> k range [kk*16, kk*16+16)
    int c4 = (t & 31) << 2;     // 4 cols
    u32 pk8[4][8];
#pragma unroll
    for (int k2 = 0; k2 < 8; ++k2) {
      float4 we = *(const float4*)&W[(kk * 16 + 2 * k2) * D + c4];
      float4 wo = *(const float4*)&W[(kk * 16 + 2 * k2 + 1) * D + c4];
      pk8[0][k2] = (u32)f2bf(we.x) | ((u32)f2bf(wo.x) << 16);
      pk8[1][k2] = (u32)f2bf(we.y) | ((u32)f2bf(wo.y) << 16);
      pk8[2][k2] = (u32)f2bf(we.z) | ((u32)f2bf(wo.z) << 16);
      pk8[3][k2] = (u32)f2bf(we.w) | ((u32)f2bf(wo.w) << 16);
    }
#pragma unroll
    for (int c = 0; c < 4; ++c) {
      *(uint4*)&Wt[(c4 + c) * LDK + kk * 16] = *(uint4*)&pk8[c][0];
      *(uint4*)&Wt[(c4 + c) * LDK + kk * 16 + 8] = *(uint4*)&pk8[c][4];
    }
  }
  {  // stage Xl (bf16), optional BN+relu
    int r = t >> 5;
    int c4 = (t & 31) << 2;
    float4 sc, sh;
    if (BN) { sc = ((const float4*)scale)[t & 31]; sh = ((const float4*)shift)[t & 31]; }
    for (int rr = r; rr < GR; rr += 8) {
      int gr = row0 + rr;
      uint2 pk = {0u, 0u};
      if (gr < n) {
        if (XBF) {
          pk = *(const uint2*)&Xb[(size_t)gr * D + c4];
          if (BN) pk = pk4(bnrelu4(unpk4(pk), sc, sh));
        } else {
          float4 v = *(const float4*)&Xf[(size_t)gr * D + c4];
          if (BN) v = bnrelu4(v, sc, sh);
          pk = pk4(v);
        }
      }
      *(uint2*)&Xl[rr * LDK + c4] = pk;
    }
  }
  __syncthreads();
  int wv = t >> 6;
  int l = t & 63;
  int lg = l >> 4;
  int li = l & 15;
  int wr = wv * 32;
  f32x4 acc[2][8];
#pragma unroll
  for (int m = 0; m < 2; ++m)
#pragma unroll
    for (int nf = 0; nf < 8; ++nf)
      acc[m][nf] = (f32x4){0.f, 0.f, 0.f, 0.f};
#pragma unroll
  for (int ks = 0; ks < 4; ++ks) {
    int k0 = ks * 32 + lg * 8;
    bf16x8 a0 = *(const bf16x8*)&Xl[(wr + li) * LDK + k0];
    bf16x8 a1 = *(const bf16x8*)&Xl[(wr + 16 + li) * LDK + k0];
#pragma unroll
    for (int nf = 0; nf < 8; ++nf) {
      bf16x8 b = *(const bf16x8*)&Wt[(nf * 16 + li) * LDK + k0];
      acc[0][nf] = __builtin_amdgcn_mfma_f32_16x16x32_bf16(a0, b, acc[0][nf], 0, 0, 0);
      acc[1][nf] = __builtin_amdgcn_mfma_f32_16x16x32_bf16(a1, b, acc[1][nf], 0, 0, 0);
    }
  }
  // Epilogue: repack fragments as bf16 into Xl [128][LDK], then coalesced store.
  __syncthreads();  // all MFMA reads of Xl/Wt done
#pragma unroll
  for (int m = 0; m < 2; ++m) {
#pragma unroll
    for (int r = 0; r < 4; ++r) {
      int rl = wr + 16 * m + lg * 4 + r;
#pragma unroll
      for (int nf = 0; nf < 8; ++nf)
        Xl[rl * LDK + nf * 16 + li] = f2bf(acc[m][nf][r]);
    }
  }
  __syncthreads();
  for (int idx = t; idx < 128 * 16; idx += 256) {  // 128 rows x 16 uint4 chunks
    int rl = idx >> 4;
    int ch = idx & 15;
    int grow = row0 + rl;
    if (grow < n)
      *(uint4*)(Ybf + (size_t)grow * D + ch * 8) = *(const uint4*)&Xl[rl * LDK + ch * 8];
  }
}

// Pull-gather, one 32-lane group per dst row, grid-stride over rows.
// Edge loop: 8-edge window with prefetched indices+weights, two 4-deep
// feat-load batches into 4 accumulators (idx->feat serial chain broken).
// L2=false (layer1): out bf16 h1pre; accumulate BN col-stats -> block partials.
// L2=true  (layer2): skip = relu(BN(h1bf)) added; out f32 (final).
template <bool L2>
__global__ __launch_bounds__(256) void k_gather(const u16* __restrict__ feat,
                                                const u16* __restrict__ h1bf,
                                                const float* __restrict__ bias,
                                                const float* __restrict__ dis,
                                                const int* __restrict__ rowptr,
                                                const u16* __restrict__ csr_src,
                                                float* __restrict__ outf,
                                                u16* __restrict__ outb, int n,
                                                const float* __restrict__ scale,
                                                const float* __restrict__ shift,
                                                float* __restrict__ partial) {
  __shared__ float s_l[8][128];
  __shared__ float q_l[8][128];
  int t = threadIdx.x;
  int lane = t & 31;
  int g = t >> 5;
  int ngroups = gridDim.x * 8;
  float4 s4 = {0.f, 0.f, 0.f, 0.f};
  float4 q4 = {0.f, 0.f, 0.f, 0.f};
  float4 bv = ((const float4*)bias)[lane];
  float4 sc, sh;
  if (L2) { sc = ((const float4*)scale)[lane]; sh = ((const float4*)shift)[lane]; }
  for (int r = blockIdx.x * 8 + g; r < n; r += ngroups) {
    int start = (r == 0) ? 0 : rowptr[r - 1];
    int end = rowptr[r];
    float dr = dis[r];
    float4 acc = bv;
    float4 sv = ldbf4(feat, (size_t)r, lane);
    acc = fma4(dr * dr, sv, acc);
    if (L2) {
      float4 h = bnrelu4(ldbf4(h1bf, (size_t)r, lane), sc, sh);
      acc.x += h.x; acc.y += h.y; acc.z += h.z; acc.w += h.w;
    }
    float4 acc1 = {0.f, 0.f, 0.f, 0.f};
    float4 acc2 = {0.f, 0.f, 0.f, 0.f};
    float4 acc3 = {0.f, 0.f, 0.f, 0.f};
    int j = start;
    for (; j + 8 <= end; j += 8) {
      int s0 = csr_src[j];
      int s1 = csr_src[j + 1];
      int s2 = csr_src[j + 2];
      int s3 = csr_src[j + 3];
      int s4i = csr_src[j + 4];
      int s5 = csr_src[j + 5];
      int s6 = csr_src[j + 6];
      int s7 = csr_src[j + 7];
      float w0 = dis[s0] * dr;
      float w1 = dis[s1] * dr;
      float w2 = dis[s2] * dr;
      float w3 = dis[s3] * dr;
      float w4 = dis[s4i] * dr;
      float w5 = dis[s5] * dr;
      float w6 = dis[s6] * dr;
      float w7 = dis[s7] * dr;
      float4 v0 = ldbf4(feat, (size_t)s0, lane);
      float4 v1 = ldbf4(feat, (size_t)s1, lane);
      float4 v2 = ldbf4(feat, (size_t)s2, lane);
      float4 v3 = ldbf4(feat, (size_t)s3, lane);
      acc = fma4(w0, v0, acc);
      acc1 = fma4(w1, v1, acc1);
      acc2 = fma4(w2, v2, acc2);
      acc3 = fma4(w3, v3, acc3);
      v0 = ldbf4(feat, (size_t)s4i, lane);
      v1 = ldbf4(feat, (size_t)s5, lane);
      v2 = ldbf4(feat, (size_t)s6, lane);
      v3 = ldbf4(feat, (size_t)s7, lane);
      acc = fma4(w4, v0, acc);
      acc1 = fma4(w5, v1, acc1);
      acc2 = fma4(w6, v2, acc2);
      acc3 = fma4(w7, v3, acc3);
    }
    for (; j + 2 <= end; j += 2) {
      int s0 = csr_src[j];
      int s1 = csr_src[j + 1];
      float w0 = dis[s0] * dr;
      float w1 = dis[s1] * dr;
      float4 v0 = ldbf4(feat, (size_t)s0, lane);
      float4 v1 = ldbf4(feat, (size_t)s1, lane);
      acc = fma4(w0, v0, acc);
      acc1 = fma4(w1, v1, acc1);
    }
    if (j < end) {
      int s0 = csr_src[j];
      float w0 = dis[s0] * dr;
      acc = fma4(w0, ldbf4(feat, (size_t)s0, lane), acc);
    }
    acc.x += acc1.x + acc2.x + acc3.x;
    acc.y += acc1.y + acc2.y + acc3.y;
    acc.z += acc1.z + acc2.z + acc3.z;
    acc.w += acc1.w + acc2.w + acc3.w;
    if (L2) {
      ((float4*)(outf + (size_t)r * D))[lane] = acc;
    } else {
      *(uint2*)(outb + (size_t)r * D + lane * 4) = pk4(acc);
      s4.x += acc.x; s4.y += acc.y; s4.z += acc.z; s4.w += acc.w;
      q4.x = fmaf(acc.x, acc.x, q4.x);
      q4.y = fmaf(acc.y, acc.y, q4.y);
      q4.z = fmaf(acc.z, acc.z, q4.z);
      q4.w = fmaf(acc.w, acc.w, q4.w);
    }
  }
  if (!L2) {
    *(float4*)&s_l[g][lane * 4] = s4;
    *(float4*)&q_l[g][lane * 4] = q4;
    __syncthreads();
    float v = 0.f;
    if (t < 128) {
#pragma unroll
      for (int gg = 0; gg < 8; ++gg) v += s_l[gg][t];
    } else {
#pragma unroll
      for (int gg = 0; gg < 8; ++gg) v += q_l[gg][t - 128];
    }
    partial[blockIdx.x * 256 + t] = v;  // [0..127]=colsum, [128..255]=colsumsq
  }
}

// Fold block partials -> mu/var -> scale/shift. One block per column.
__global__ __launch_bounds__(256) void k_bnreduce(const float* __restrict__ partial,
                                                  int nbp,
                                                  const float* __restrict__ gamma,
                                                  const float* __restrict__ beta,
                                                  float* __restrict__ scale,
                                                  float* __restrict__ shift, int n) {
  __shared__ float rs[256], rq[256];
  int c = blockIdx.x;
  int t = threadIdx.x;
  float s = 0.f, q = 0.f;
  for (int b = t; b < nbp; b += 256) {
    s += partial[b * 256 + c];
    q += partial[b * 256 + 128 + c];
  }
  rs[t] = s; rq[t] = q;
  __syncthreads();
  for (int st = 128; st > 0; st >>= 1) {
    if (t < st) { rs[t] += rs[t + st]; rq[t] += rq[t + st]; }
    __syncthreads();
  }
  if (t == 0) {
    float inv_n = 1.0f / (float)n;
    float mu = rs[0] * inv_n;
    float var = rq[0] * inv_n - mu * mu;
    float sc = gamma[c] * rsqrtf(var + 1e-5f);
    scale[c] = sc;
    shift[c] = beta[c] - mu * sc;
  }
}

extern "C" void kernel_launch(void* const* d_in, const int* in_sizes, int n_in,
                              void* d_out, int out_size, void* d_ws, size_t ws_size,
                              hipStream_t stream) {
  const float* x     = (const float*)d_in[0];
  const int*   ei32  = (const int*)d_in[1];
  const i64*   ei64  = (const i64*)d_in[1];
  const float* W1    = (const float*)d_in[2];
  const float* b1    = (const float*)d_in[3];
  const float* W2    = (const float*)d_in[4];
  const float* b2    = (const float*)d_in[5];
  const float* gamma = (const float*)d_in[6];
  const float* beta  = (const float*)d_in[7];
  float* out = (float*)d_out;

  const int n = in_sizes[0] / D;  // 50000
  const int e = in_sizes[1] / 2;  // 800000
  const int GB1 = 2048;           // persistent gather1 blocks
  const int NB = (n + RPB - 1) / RPB;  // buckets (98)
  const int NC = (e + CH - 1) / CH;    // chunks (196)

  // Workspace layout (~31 MB)
  size_t npad = ((size_t)n + 255) & ~255ULL;
  size_t epad = ((size_t)e + 255) & ~255ULL;
  char* p = (char*)d_ws;
  float* dis      = (float*)p; p += npad * 4;
  int*   rowptr   = (int*)p;   p += npad * 4;
  u16*   csr16    = (u16*)p;   p += epad * 2;
  u32*   pairs    = (u32*)p;   p += epad * 4;
  int*   hist     = (int*)p;   p += (size_t)NC * NB * 4;
  int*   chunkoff = (int*)p;   p += (size_t)NC * NB * 4;
  int*   bucketbase = (int*)p; p += ((size_t)NB + 1 + 63) / 64 * 64 * 4;
  u16*   hwbf     = (u16*)p;   p += (size_t)n * D * 2;  // gemm out (hw1, then hw2)
  u16*   h1bf     = (u16*)p;   p += (size_t)n * D * 2;  // h1pre (bf16)
  float* partial  = (float*)p; p += (size_t)GB1 * 256 * 4;
  float* scale    = (float*)p; p += D * 4;
  float* shift    = (float*)p; p += D * 4;
  int*   flag     = (int*)p;   p += 256 * 4;

  int gb = (n + 7) / 8;          // gather2: 8 rows per 256-thread block
  int mb = (n + GR - 1) / GR;    // gemm: 128 rows per block

  // CSR build: atomic-free bucket sort (LDS-local randomness only)
  k_detect<<<1, 256, 0, stream>>>((const unsigned*)d_in[1], flag);
  k_hist<<<NC, 256, 0, stream>>>(ei32, ei64, flag, e, NB, hist);
  if (NC * NB <= MAXHB && NB <= 128)
    k_bscan<<<1, 1024, 0, stream>>>(hist, NC, NB, chunkoff, bucketbase);
  else
    k_bscan_slow<<<1, 128, 0, stream>>>(hist, NC, NB, chunkoff, bucketbase);
  k_bin<<<NC, 256, 0, stream>>>(ei32, ei64, flag, e, NB, chunkoff, pairs);
  k_csr<<<NB, 512, 0, stream>>>(pairs, bucketbase, n, rowptr, dis, csr16);

  // layer 1: conv (MFMA) -> gather (+fused BN stats) -> scale/shift
  k_gemm<false, false><<<mb, 256, 0, stream>>>(x, nullptr, W1, hwbf, n, nullptr, nullptr);
  k_gather<false><<<GB1, 256, 0, stream>>>(hwbf, nullptr, b1, dis, rowptr, csr16,
                                           nullptr, h1bf, n, nullptr, nullptr, partial);
  k_bnreduce<<<D, 256, 0, stream>>>(partial, GB1, gamma, beta, scale, shift, n);

  // layer 2: conv (BN+relu fused, bf16 in) + gather with fused BN'd skip
  k_gemm<true, true><<<mb, 256, 0, stream>>>(nullptr, h1bf, W2, hwbf, n, scale, shift);
  k_gather<true><<<gb, 256, 0, stream>>>(hwbf, h1bf, b2, dis, rowptr, csr16,
                                         out, nullptr, n, scale, shift, nullptr);
}